// Round 4
// baseline (13.737 us; speedup 1.0000x reference)
//
#include <hip/hip_runtime.h>
#include <hip/hip_bf16.h>

// LengthRegulator, scatter formulation (R4: vectorized LDS zero + copy-out):
// Each block owns (row, chunk of CHUNK output positions).
// Phase 1: row cumsum — per-thread local prefix (16 items in registers) +
//          wave shfl-scan + cross-wave LDS combine (1 barrier).
// Phase 2: zero LDS out-tile (int4); each thread scatters tok+1 over its
//          tokens' clipped ranges [cs[tok-1], cs[tok]) ∩ chunk (regs only).
// Phase 3: copy LDS tile -> global, int4 main body with scalar head/tail
//          to handle (row*T_mel + base) % 4 misalignment.

#define COLS 4096
#define THREADS 256
#define CHUNK 4096
#define ITEMS 16            // COLS / THREADS
#define NWAVES 4            // THREADS / 64

__global__ __launch_bounds__(THREADS) void lr_scatter_kernel(
    const int* __restrict__ dur, int* __restrict__ out, int T_mel) {
    __shared__ int out_lds[CHUNK];   // 16 KB output tile
    __shared__ int wsum[NWAVES];

    const int row = blockIdx.y;
    const int t = threadIdx.x;
    const int lane = t & 63;
    const int wid = t >> 6;
    const int base = blockIdx.x * CHUNK;

    // ---- load 16 durations into registers ----
    const int4* d4 = reinterpret_cast<const int4*>(dur + (size_t)row * COLS) + t * 4;
    int v[ITEMS];
#pragma unroll
    for (int i = 0; i < 4; ++i) {
        int4 a = d4[i];
        v[i * 4 + 0] = a.x;
        v[i * 4 + 1] = a.y;
        v[i * 4 + 2] = a.z;
        v[i * 4 + 3] = a.w;
    }

    // ---- zero the output tile, vectorized (ds_write_b128, conflict-free) ----
    int4* z4 = reinterpret_cast<int4*>(out_lds);
#pragma unroll
    for (int j = 0; j < CHUNK / 4 / THREADS; ++j)   // 4 iterations
        z4[j * THREADS + t] = make_int4(0, 0, 0, 0);

    // ---- local inclusive prefix over 16 items ----
#pragma unroll
    for (int i = 1; i < ITEMS; ++i) v[i] += v[i - 1];
    const int mysum = v[ITEMS - 1];

    // ---- wave inclusive scan of thread sums (6 shfl steps, no barriers) ----
    int inc = mysum;
#pragma unroll
    for (int off = 1; off < 64; off <<= 1) {
        int n = __shfl_up(inc, off, 64);
        if (lane >= off) inc += n;
    }
    if (lane == 63) wsum[wid] = inc;
    __syncthreads();   // also guarantees out_lds zeroing is complete

    int wbase = 0;
#pragma unroll
    for (int w = 0; w < NWAVES; ++w) wbase += (w < wid) ? wsum[w] : 0;
    const int excl = wbase + inc - mysum;   // exclusive prefix for this thread's first token

    // ---- scatter tok+1 over clipped ranges ----
    const int chunk_end = base + CHUNK;
    if (excl < chunk_end && excl + mysum > base) {   // thread's span intersects chunk
        int prev = excl;
#pragma unroll
        for (int i = 0; i < ITEMS; ++i) {
            const int cur = excl + v[i];
            const int s0 = prev > base ? prev : base;
            const int e0 = cur < chunk_end ? cur : chunk_end;
            const int val = t * ITEMS + i + 1;
            for (int q = s0; q < e0; ++q) out_lds[q - base] = val;
            prev = cur;
        }
    }
    __syncthreads();

    // ---- copy to global: scalar head to 16B alignment, int4 body, scalar tail ----
    const int limit0 = T_mel - base;
    const int limit = limit0 < CHUNK ? limit0 : CHUNK;
    if (limit <= 0) return;

    int* __restrict__ orow = out + (size_t)row * T_mel + base;
    const int mis = (int)(((size_t)row * (size_t)T_mel + (size_t)base) & 3);
    int head = (4 - mis) & 3;
    if (head > limit) head = limit;

    if (t < head) orow[t] = out_lds[t];

    const int nvec = (limit - head) >> 2;            // # int4 stores (<= 1024)
    int4* __restrict__ o4 = reinterpret_cast<int4*>(orow + head);
#pragma unroll
    for (int j = 0; j < CHUNK / 4 / THREADS; ++j) {  // 4 iterations
        const int idx = j * THREADS + t;
        if (idx < nvec) {
            const int s = head + idx * 4;
            o4[idx] = make_int4(out_lds[s], out_lds[s + 1], out_lds[s + 2], out_lds[s + 3]);
        }
    }

    const int done = head + (nvec << 2);
    const int rem = limit - done;                    // 0..3
    if (t < rem) orow[done + t] = out_lds[done + t];
}

extern "C" void kernel_launch(void* const* d_in, const int* in_sizes, int n_in,
                              void* d_out, int out_size, void* d_ws, size_t ws_size,
                              hipStream_t stream) {
    const int* dur = (const int*)d_in[0];
    int* out = (int*)d_out;

    const int rows = in_sizes[0] / COLS;   // 32
    const int T_mel = out_size / rows;

    dim3 grid((T_mel + CHUNK - 1) / CHUNK, rows);
    lr_scatter_kernel<<<grid, THREADS, 0, stream>>>(dur, out, T_mel);
}